// Round 1
// 558.023 us; speedup vs baseline: 1.0435x; 1.0435x over previous
//
#include <hip/hip_runtime.h>

#define NTOK 256
#define TT 128
#define DD 64
#define HH 8

typedef __bf16 bf16_t;
typedef bf16_t bf16x8 __attribute__((ext_vector_type(8)));
typedef bf16_t bf16x4 __attribute__((ext_vector_type(4)));
typedef float f32x4 __attribute__((ext_vector_type(4)));

__device__ __forceinline__ bf16x8 load_f32x8_as_bf16(const float* p) {
    float4 a = *reinterpret_cast<const float4*>(p);
    float4 b = *reinterpret_cast<const float4*>(p + 4);
    bf16x8 r;
    r[0] = (bf16_t)a.x; r[1] = (bf16_t)a.y; r[2] = (bf16_t)a.z; r[3] = (bf16_t)a.w;
    r[4] = (bf16_t)b.x; r[5] = (bf16_t)b.y; r[6] = (bf16_t)b.z; r[7] = (bf16_t)b.w;
    return r;
}

// ---------------------------------------------------------------------------
// Kernel 1: QKV projection, one block per (t,h), 256 threads = 4 waves.
// Wave w computes rows 64w..64w+63. C-fragments are staged in a per-wave LDS
// tile (stride 72 bf16 -> 2-way-free banks), then written back with fully
// coalesced bf16x8 stores (1 KB per wave instruction).
// Q is pre-scaled by 1/sqrt(64). V is produced transposed [d][n] via swapped
// MFMA operands (D[d][n] = W-row x x-row).
// ---------------------------------------------------------------------------
__global__ __launch_bounds__(256, 2)
void qkv_kernel(const float* __restrict__ x,
                const float* __restrict__ Wq, const float* __restrict__ bq,
                const float* __restrict__ Wk, const float* __restrict__ bk,
                const float* __restrict__ Wv, const float* __restrict__ bv,
                bf16_t* __restrict__ q_ws, bf16_t* __restrict__ k_ws,
                bf16_t* __restrict__ vt_ws) {
    __shared__ __align__(16) bf16_t st[4][64][72];
    const int t    = blockIdx.x >> 3;
    const int h    = blockIdx.x & 7;
    const int wave = threadIdx.x >> 6;
    const int lane = threadIdx.x & 63;
    const int l15  = lane & 15, quad = lane >> 4;
    const int rrow = lane >> 3;          // write-back: row-within-8
    const int rcol = (lane & 7) * 8;     // write-back: col (8 bf16 = 16B)

    // A-fragments of x (rows for this wave), converted to bf16.
    bf16x8 ax[4][2];
#pragma unroll
    for (int mt = 0; mt < 4; ++mt) {
        int n = (wave * 4 + mt) * 16 + l15;
        const float* xp = x + ((size_t)n * TT + t) * DD;
#pragma unroll
        for (int kt = 0; kt < 2; ++kt)
            ax[mt][kt] = load_f32x8_as_bf16(xp + kt * 32 + quad * 8);
    }

    const size_t thbase = (size_t)blockIdx.x * (NTOK * DD);
    const float* Ws[3] = {Wq, Wk, Wv};
    const float* bs[3] = {bq, bk, bv};

#pragma unroll
    for (int mat = 0; mat < 3; ++mat) {
        // B-fragments: rows d of W (row-major (HD, D))
        bf16x8 bw[4][2];
#pragma unroll
        for (int dt = 0; dt < 4; ++dt) {
            const float* wp = Ws[mat] + ((size_t)(h * DD + dt * 16 + l15)) * DD;
#pragma unroll
            for (int kt = 0; kt < 2; ++kt)
                bw[dt][kt] = load_f32x8_as_bf16(wp + kt * 32 + quad * 8);
        }

        if (mat < 2) {
            float bias[4];
#pragma unroll
            for (int dt = 0; dt < 4; ++dt)
                bias[dt] = bs[mat][h * DD + dt * 16 + l15];
            const float qs = (mat == 0) ? 0.125f : 1.0f;
#pragma unroll
            for (int mt = 0; mt < 4; ++mt) {
#pragma unroll
                for (int dt = 0; dt < 4; ++dt) {
                    f32x4 acc = {0.f, 0.f, 0.f, 0.f};
#pragma unroll
                    for (int kt = 0; kt < 2; ++kt)
                        acc = __builtin_amdgcn_mfma_f32_16x16x32_bf16(
                            ax[mt][kt], bw[dt][kt], acc, 0, 0, 0);
#pragma unroll
                    for (int r = 0; r < 4; ++r)
                        st[wave][mt * 16 + quad * 4 + r][dt * 16 + l15] =
                            (bf16_t)((acc[r] + bias[dt]) * qs);
                }
            }
            // coalesced write-back: 8 instrs x (8 rows x 128B)
            bf16_t* dst = (mat == 0 ? q_ws : k_ws) + thbase + (size_t)(wave * 64) * DD;
#pragma unroll
            for (int i = 0; i < 8; ++i) {
                int row = i * 8 + rrow;
                *reinterpret_cast<bf16x8*>(dst + (size_t)row * DD + rcol) =
                    *reinterpret_cast<const bf16x8*>(&st[wave][row][rcol]);
            }
        } else {
            // V via swapped MFMA: D[d][n-local]; bias indexed by d = dt*16+quad*4+r
            f32x4 bvv[4];
#pragma unroll
            for (int dt = 0; dt < 4; ++dt)
                bvv[dt] = *reinterpret_cast<const f32x4*>(bv + h * DD + dt * 16 + quad * 4);
#pragma unroll
            for (int dt = 0; dt < 4; ++dt) {
#pragma unroll
                for (int mt = 0; mt < 4; ++mt) {
                    f32x4 acc = {0.f, 0.f, 0.f, 0.f};
#pragma unroll
                    for (int kt = 0; kt < 2; ++kt)
                        acc = __builtin_amdgcn_mfma_f32_16x16x32_bf16(
                            bw[dt][kt], ax[mt][kt], acc, 0, 0, 0);
#pragma unroll
                    for (int r = 0; r < 4; ++r)
                        st[wave][dt * 16 + quad * 4 + r][mt * 16 + l15] =
                            (bf16_t)(acc[r] + bvv[dt][r]);
                }
            }
            // vt[d][n]: each wave owns the n-chunk 64w..64w+63 of every d-row
#pragma unroll
            for (int i = 0; i < 8; ++i) {
                int row = i * 8 + rrow;  // d
                *reinterpret_cast<bf16x8*>(
                    vt_ws + thbase + (size_t)row * NTOK + wave * 64 + rcol) =
                    *reinterpret_cast<const bf16x8*>(&st[wave][row][rcol]);
            }
        }
    }
}

// ---------------------------------------------------------------------------
// Kernel 2: attention, one block per (t,h), 256 threads = 4 waves, no barriers.
// Swapped QK^T: s = mfma(K_frag, Q_frag) -> lane (l15,quad) owns q-row q0+l15,
// k = j*16+quad*4+r. aw is loaded as aligned float4 directly in fragment
// order; softmax is lane-local + 2 shfls; P staged as bf16x4; O = P V; out is
// transposed through LDS and stored as 256B-contiguous float4 rows.
// ---------------------------------------------------------------------------
__global__ __launch_bounds__(256, 2)
void attn_kernel(const float* __restrict__ aw,
                 const bf16_t* __restrict__ q_ws, const bf16_t* __restrict__ k_ws,
                 const bf16_t* __restrict__ vt_ws, float* __restrict__ out) {
    __shared__ __align__(16) bf16_t ps[4][16][264];   // P staging, per wave
    __shared__ __align__(16) float ost[4][16][68];    // out transpose, per wave
    const int t    = blockIdx.x >> 3;
    const int h    = blockIdx.x & 7;
    const int wave = threadIdx.x >> 6;
    const int lane = threadIdx.x & 63;
    const int l15  = lane & 15, quad = lane >> 4;

    const size_t thbase = (size_t)blockIdx.x * (NTOK * DD);
    const bf16_t* qp = q_ws + thbase;
    const bf16_t* kp = k_ws + thbase;
    const bf16_t* vp = vt_ws + thbase;
    const float*  wp = aw + (size_t)blockIdx.x * ((size_t)NTOK * NTOK);

    for (int it = 0; it < 4; ++it) {
        const int q0 = (wave * 4 + it) * 16;

        // Q fragments (B-operand): rows q0+l15, pre-scaled by 1/8 in kernel 1
        bf16x8 qf[2];
#pragma unroll
        for (int kt = 0; kt < 2; ++kt)
            qf[kt] = *reinterpret_cast<const bf16x8*>(
                qp + (size_t)(q0 + l15) * DD + kt * 32 + quad * 8);

        const float* wrow = wp + (size_t)(q0 + l15) * NTOK + quad * 4;

        // S^T tiles: s[j][r] = S[q0+l15][j*16+quad*4+r], aw applied per float4
        f32x4 s[16];
        float mx = -1e30f;
#pragma unroll
        for (int j = 0; j < 16; ++j) {
            f32x4 w4 = *reinterpret_cast<const f32x4*>(wrow + j * 16);
            f32x4 acc = {0.f, 0.f, 0.f, 0.f};
#pragma unroll
            for (int kt = 0; kt < 2; ++kt) {
                bf16x8 kf = *reinterpret_cast<const bf16x8*>(
                    kp + (size_t)(j * 16 + l15) * DD + kt * 32 + quad * 8);
                acc = __builtin_amdgcn_mfma_f32_16x16x32_bf16(kf, qf[kt], acc, 0, 0, 0);
            }
            acc *= w4;
            s[j] = acc;
            mx = fmaxf(mx, fmaxf(fmaxf(acc[0], acc[1]), fmaxf(acc[2], acc[3])));
        }
        // row max across the 4 quads holding this q-row
        mx = fmaxf(mx, __shfl_xor(mx, 16, 64));
        mx = fmaxf(mx, __shfl_xor(mx, 32, 64));

        float sm = 0.f;
#pragma unroll
        for (int j = 0; j < 16; ++j) {
#pragma unroll
            for (int r = 0; r < 4; ++r) {
                float e = __expf(s[j][r] - mx);
                s[j][r] = e;
                sm += e;
            }
        }
        sm += __shfl_xor(sm, 16, 64);
        sm += __shfl_xor(sm, 32, 64);
        const float inv = 1.f / sm;

        // stage P: row = q-local (l15), col = k; bf16x4 (8B) writes
#pragma unroll
        for (int j = 0; j < 16; ++j) {
            bf16x4 pk;
#pragma unroll
            for (int r = 0; r < 4; ++r) pk[r] = (bf16_t)(s[j][r] * inv);
            *reinterpret_cast<bf16x4*>(&ps[wave][l15][j * 16 + quad * 4]) = pk;
        }

        // O = P V : A-frags from ps (row l15), B-frags from transposed V
        f32x4 o[4];
#pragma unroll
        for (int dt = 0; dt < 4; ++dt) o[dt] = (f32x4){0.f, 0.f, 0.f, 0.f};
#pragma unroll
        for (int kt = 0; kt < 8; ++kt) {
            bf16x8 ap = *reinterpret_cast<const bf16x8*>(&ps[wave][l15][kt * 32 + quad * 8]);
#pragma unroll
            for (int dt = 0; dt < 4; ++dt) {
                bf16x8 bvf = *reinterpret_cast<const bf16x8*>(
                    vp + (size_t)(dt * 16 + l15) * NTOK + kt * 32 + quad * 8);
                o[dt] = __builtin_amdgcn_mfma_f32_16x16x32_bf16(ap, bvf, o[dt], 0, 0, 0);
            }
        }

        // transpose O through LDS, then 256B-contiguous float4 row stores
#pragma unroll
        for (int dt = 0; dt < 4; ++dt) {
#pragma unroll
            for (int r = 0; r < 4; ++r)
                ost[wave][quad * 4 + r][dt * 16 + l15] = o[dt][r];
        }
#pragma unroll
        for (int i = 0; i < 4; ++i) {
            int row = i * 4 + quad;  // q-local 0..15
            f32x4 v = *reinterpret_cast<const f32x4*>(&ost[wave][row][l15 * 4]);
            *reinterpret_cast<f32x4*>(
                out + (((size_t)h * NTOK + q0 + row) * TT + t) * DD + l15 * 4) = v;
        }
    }
}

extern "C" void kernel_launch(void* const* d_in, const int* in_sizes, int n_in,
                              void* d_out, int out_size, void* d_ws, size_t ws_size,
                              hipStream_t stream) {
    const float* x  = (const float*)d_in[0];
    const float* Wq = (const float*)d_in[1];
    const float* bq = (const float*)d_in[2];
    const float* Wk = (const float*)d_in[3];
    const float* bk = (const float*)d_in[4];
    const float* Wv = (const float*)d_in[5];
    const float* bv = (const float*)d_in[6];
    const float* aw = (const float*)d_in[7];
    float* out = (float*)d_out;

    const size_t per = (size_t)TT * HH * NTOK * DD;  // 16,777,216 elems
    bf16_t* q_ws  = (bf16_t*)d_ws;
    bf16_t* k_ws  = q_ws + per;
    bf16_t* vt_ws = k_ws + per;
    // ws use: 3 * per * 2B = 100.7 MB

    qkv_kernel<<<TT * HH, 256, 0, stream>>>(x, Wq, bq, Wk, bk, Wv, bv,
                                            q_ws, k_ws, vt_ws);
    attn_kernel<<<TT * HH, 256, 0, stream>>>(aw, q_ws, k_ws, vt_ws, out);
}

// Round 2
// 435.219 us; speedup vs baseline: 1.3380x; 1.2822x over previous
//
#include <hip/hip_runtime.h>

#define NTOK 256
#define TT 128
#define DD 64
#define HH 8

typedef __bf16 bf16_t;
typedef bf16_t bf16x8 __attribute__((ext_vector_type(8)));
typedef bf16_t bf16x4 __attribute__((ext_vector_type(4)));
typedef float f32x4 __attribute__((ext_vector_type(4)));

__device__ __forceinline__ bf16x8 load_f32x8_as_bf16(const float* p) {
    float4 a = *reinterpret_cast<const float4*>(p);
    float4 b = *reinterpret_cast<const float4*>(p + 4);
    bf16x8 r;
    r[0] = (bf16_t)a.x; r[1] = (bf16_t)a.y; r[2] = (bf16_t)a.z; r[3] = (bf16_t)a.w;
    r[4] = (bf16_t)b.x; r[5] = (bf16_t)b.y; r[6] = (bf16_t)b.z; r[7] = (bf16_t)b.w;
    return r;
}

// XOR swizzle: permute 16B slots within a row by the low 3 row bits.
// Applied identically on write and read -> bijective, bank-floor access.
__device__ __forceinline__ int swz(int row, int stride, int colbyte) {
    return row * stride + (colbyte ^ ((row & 7) << 4));
}

// ---------------------------------------------------------------------------
// Fused QKV + spatial attention. One block per (t,h): 1024 blocks x 512 thr
// (8 waves). LDS = 128 KiB: K [256 rows x 128B], V^T [64 rows x 512B], and
// 8 KiB per-wave scratch (Q transpose -> P staging -> out transpose).
// Phase 1: Q/K/V via MFMA straight into LDS (Q kept in registers, pre-scaled).
// Phase 2: swapped QK^T (lane owns one q-row), aw as prefetched float4
// stream, softmax lane-local + 2 shfls, P staged bf16, O = P V, out stored
// as 256B-contiguous float4 rows. Single __syncthreads() in the kernel.
// ---------------------------------------------------------------------------
__global__ __launch_bounds__(512, 2)
void fused_kernel(const float* __restrict__ x,
                  const float* __restrict__ Wq, const float* __restrict__ bq,
                  const float* __restrict__ Wk, const float* __restrict__ bk,
                  const float* __restrict__ Wv, const float* __restrict__ bv,
                  const float* __restrict__ aw, float* __restrict__ out) {
    __shared__ __align__(16) char k_s[256 * 128];   // K[n][d], swizzled rows
    __shared__ __align__(16) char vt_s[64 * 512];   // V^T[d][n], swizzled rows
    __shared__ __align__(16) char un[8][8192];      // per-wave scratch

    const int t    = blockIdx.x >> 3;
    const int h    = blockIdx.x & 7;
    const int wave = threadIdx.x >> 6;
    const int lane = threadIdx.x & 63;
    const int l15  = lane & 15, quad = lane >> 4;

    // ---------------- phase 1: QKV projection into LDS ----------------
    // x fragments: this wave owns token rows 32w..32w+31 (2 m-tiles)
    bf16x8 ax[2][2];
#pragma unroll
    for (int mt = 0; mt < 2; ++mt) {
        int n = wave * 32 + mt * 16 + l15;
        const float* xp = x + ((size_t)n * TT + t) * DD;
#pragma unroll
        for (int kt = 0; kt < 2; ++kt)
            ax[mt][kt] = load_f32x8_as_bf16(xp + kt * 32 + quad * 8);
    }

    bf16x8 qf[2][2];  // Q B-fragments for phase 2 (lane l15 = q-row)

    // --- Q: stage through per-wave scratch, keep in registers, scale 1/8 ---
    {
        bf16x8 bw[4][2];
        float bias[4];
#pragma unroll
        for (int dt = 0; dt < 4; ++dt) {
            const float* wp = Wq + ((size_t)(h * DD + dt * 16 + l15)) * DD;
#pragma unroll
            for (int kt = 0; kt < 2; ++kt)
                bw[dt][kt] = load_f32x8_as_bf16(wp + kt * 32 + quad * 8);
            bias[dt] = bq[h * DD + dt * 16 + l15];
        }
        char* qs = un[wave];  // 32 rows x 128B, swizzled
#pragma unroll
        for (int mt = 0; mt < 2; ++mt) {
#pragma unroll
            for (int dt = 0; dt < 4; ++dt) {
                f32x4 acc = {0.f, 0.f, 0.f, 0.f};
#pragma unroll
                for (int kt = 0; kt < 2; ++kt)
                    acc = __builtin_amdgcn_mfma_f32_16x16x32_bf16(
                        ax[mt][kt], bw[dt][kt], acc, 0, 0, 0);
#pragma unroll
                for (int r = 0; r < 4; ++r) {
                    int lr = mt * 16 + quad * 4 + r;
                    *reinterpret_cast<bf16_t*>(qs + swz(lr, 128, (dt * 16 + l15) * 2)) =
                        (bf16_t)((acc[r] + bias[dt]) * 0.125f);
                }
            }
        }
#pragma unroll
        for (int it = 0; it < 2; ++it) {
            int lr = it * 16 + l15;
#pragma unroll
            for (int kt = 0; kt < 2; ++kt)
                qf[it][kt] = *reinterpret_cast<const bf16x8*>(
                    qs + swz(lr, 128, kt * 64 + quad * 16));
        }
    }

    // --- K: MFMA C-fragments straight into swizzled k_s ---
    {
        bf16x8 bw[4][2];
        float bias[4];
#pragma unroll
        for (int dt = 0; dt < 4; ++dt) {
            const float* wp = Wk + ((size_t)(h * DD + dt * 16 + l15)) * DD;
#pragma unroll
            for (int kt = 0; kt < 2; ++kt)
                bw[dt][kt] = load_f32x8_as_bf16(wp + kt * 32 + quad * 8);
            bias[dt] = bk[h * DD + dt * 16 + l15];
        }
#pragma unroll
        for (int mt = 0; mt < 2; ++mt) {
#pragma unroll
            for (int dt = 0; dt < 4; ++dt) {
                f32x4 acc = {0.f, 0.f, 0.f, 0.f};
#pragma unroll
                for (int kt = 0; kt < 2; ++kt)
                    acc = __builtin_amdgcn_mfma_f32_16x16x32_bf16(
                        ax[mt][kt], bw[dt][kt], acc, 0, 0, 0);
#pragma unroll
                for (int r = 0; r < 4; ++r) {
                    int n = wave * 32 + mt * 16 + quad * 4 + r;
                    *reinterpret_cast<bf16_t*>(k_s + swz(n, 128, (dt * 16 + l15) * 2)) =
                        (bf16_t)(acc[r] + bias[dt]);
                }
            }
        }
    }

    // --- V: swapped MFMA -> C[d][n], straight into swizzled vt_s ---
    {
        bf16x8 bw[4][2];
#pragma unroll
        for (int dt = 0; dt < 4; ++dt) {
            const float* wp = Wv + ((size_t)(h * DD + dt * 16 + l15)) * DD;
#pragma unroll
            for (int kt = 0; kt < 2; ++kt)
                bw[dt][kt] = load_f32x8_as_bf16(wp + kt * 32 + quad * 8);
        }
        f32x4 bvv[4];
#pragma unroll
        for (int dt = 0; dt < 4; ++dt)
            bvv[dt] = *reinterpret_cast<const f32x4*>(bv + h * DD + dt * 16 + quad * 4);
#pragma unroll
        for (int dt = 0; dt < 4; ++dt) {
#pragma unroll
            for (int mt = 0; mt < 2; ++mt) {
                f32x4 acc = {0.f, 0.f, 0.f, 0.f};
#pragma unroll
                for (int kt = 0; kt < 2; ++kt)
                    acc = __builtin_amdgcn_mfma_f32_16x16x32_bf16(
                        bw[dt][kt], ax[mt][kt], acc, 0, 0, 0);
#pragma unroll
                for (int r = 0; r < 4; ++r) {
                    int d = dt * 16 + quad * 4 + r;
                    int cb = (wave * 32 + mt * 16 + l15) * 2;
                    *reinterpret_cast<bf16_t*>(vt_s + swz(d, 512, cb)) =
                        (bf16_t)(acc[r] + bvv[dt][r]);
                }
            }
        }
    }

    __syncthreads();

    // ---------------- phase 2: attention ----------------
    const float* wp = aw + (size_t)blockIdx.x * ((size_t)NTOK * NTOK);

    for (int it = 0; it < 2; ++it) {
        const int q0 = wave * 32 + it * 16;
        const float* wrow = wp + (size_t)(q0 + l15) * NTOK + quad * 4;

        // issue ALL aw loads for this it up front (16 KB/wave in flight)
        f32x4 w4v[16];
#pragma unroll
        for (int j = 0; j < 16; ++j)
            w4v[j] = *reinterpret_cast<const f32x4*>(wrow + j * 16);

        // S^T: s[j][r] = S[q0+l15][j*16+quad*4+r] (swapped operands)
        f32x4 s[16];
        float mx = -1e30f;
#pragma unroll
        for (int j = 0; j < 16; ++j) {
            f32x4 acc = {0.f, 0.f, 0.f, 0.f};
#pragma unroll
            for (int kt = 0; kt < 2; ++kt) {
                int kn = j * 16 + l15;
                bf16x8 kf = *reinterpret_cast<const bf16x8*>(
                    k_s + swz(kn, 128, kt * 64 + quad * 16));
                acc = __builtin_amdgcn_mfma_f32_16x16x32_bf16(kf, qf[it][kt], acc, 0, 0, 0);
            }
            acc *= w4v[j];
            s[j] = acc;
            mx = fmaxf(mx, fmaxf(fmaxf(acc[0], acc[1]), fmaxf(acc[2], acc[3])));
        }
        mx = fmaxf(mx, __shfl_xor(mx, 16, 64));
        mx = fmaxf(mx, __shfl_xor(mx, 32, 64));

        float sm = 0.f;
#pragma unroll
        for (int j = 0; j < 16; ++j) {
#pragma unroll
            for (int r = 0; r < 4; ++r) {
                float e = __expf(s[j][r] - mx);
                s[j][r] = e;
                sm += e;
            }
        }
        sm += __shfl_xor(sm, 16, 64);
        sm += __shfl_xor(sm, 32, 64);
        const float inv = 1.f / sm;

        // stage P in per-wave scratch: 16 rows x 512B, swizzled
        char* ps = un[wave];
#pragma unroll
        for (int j = 0; j < 16; ++j) {
            bf16x4 pk;
#pragma unroll
            for (int r = 0; r < 4; ++r) pk[r] = (bf16_t)(s[j][r] * inv);
            *reinterpret_cast<bf16x4*>(ps + swz(l15, 512, j * 32 + quad * 8)) = pk;
        }

        // O = P V
        f32x4 o[4];
#pragma unroll
        for (int dt = 0; dt < 4; ++dt) o[dt] = (f32x4){0.f, 0.f, 0.f, 0.f};
#pragma unroll
        for (int kt = 0; kt < 8; ++kt) {
            bf16x8 ap = *reinterpret_cast<const bf16x8*>(
                ps + swz(l15, 512, kt * 64 + quad * 16));
#pragma unroll
            for (int dt = 0; dt < 4; ++dt) {
                int d = dt * 16 + l15;
                bf16x8 bvf = *reinterpret_cast<const bf16x8*>(
                    vt_s + swz(d, 512, kt * 64 + quad * 16));
                o[dt] = __builtin_amdgcn_mfma_f32_16x16x32_bf16(ap, bvf, o[dt], 0, 0, 0);
            }
        }

        // transpose O through scratch (reuse, wave-private), 16 rows x 256B
        char* ost = un[wave];
#pragma unroll
        for (int dt = 0; dt < 4; ++dt) {
#pragma unroll
            for (int r = 0; r < 4; ++r) {
                int row = quad * 4 + r;
                *reinterpret_cast<float*>(ost + swz(row, 256, (dt * 16 + l15) * 4)) =
                    o[dt][r];
            }
        }
#pragma unroll
        for (int i = 0; i < 4; ++i) {
            int row = i * 4 + quad;  // q-local 0..15
            f32x4 v = *reinterpret_cast<const f32x4*>(ost + swz(row, 256, l15 * 16));
            *reinterpret_cast<f32x4*>(
                out + (((size_t)h * NTOK + q0 + row) * TT + t) * DD + l15 * 4) = v;
        }
    }
}

extern "C" void kernel_launch(void* const* d_in, const int* in_sizes, int n_in,
                              void* d_out, int out_size, void* d_ws, size_t ws_size,
                              hipStream_t stream) {
    const float* x  = (const float*)d_in[0];
    const float* Wq = (const float*)d_in[1];
    const float* bq = (const float*)d_in[2];
    const float* Wk = (const float*)d_in[3];
    const float* bk = (const float*)d_in[4];
    const float* Wv = (const float*)d_in[5];
    const float* bv = (const float*)d_in[6];
    const float* aw = (const float*)d_in[7];
    float* out = (float*)d_out;

    fused_kernel<<<TT * HH, 512, 0, stream>>>(x, Wq, bq, Wk, bk, Wv, bv, aw, out);
}

// Round 4
// 412.862 us; speedup vs baseline: 1.4104x; 1.0542x over previous
//
#include <hip/hip_runtime.h>

#define NTOK 256
#define TT 128
#define DD 64
#define HH 8

typedef __bf16 bf16_t;
typedef bf16_t bf16x8 __attribute__((ext_vector_type(8)));
typedef bf16_t bf16x4 __attribute__((ext_vector_type(4)));
typedef float f32x4 __attribute__((ext_vector_type(4)));

__device__ __forceinline__ bf16x8 load_f32x8_as_bf16(const float* p) {
    float4 a = *reinterpret_cast<const float4*>(p);
    float4 b = *reinterpret_cast<const float4*>(p + 4);
    bf16x8 r;
    r[0] = (bf16_t)a.x; r[1] = (bf16_t)a.y; r[2] = (bf16_t)a.z; r[3] = (bf16_t)a.w;
    r[4] = (bf16_t)b.x; r[5] = (bf16_t)b.y; r[6] = (bf16_t)b.z; r[7] = (bf16_t)b.w;
    return r;
}

// XOR swizzle: permute 16B slots within a row by the low 3 row bits.
// Applied identically on write and read -> bijective, bank-floor access.
__device__ __forceinline__ int swz(int row, int stride, int colbyte) {
    return row * stride + (colbyte ^ ((row & 7) << 4));
}

// 8-byte cross-lane shuffle (two dword bpermutes). All lanes execute.
__device__ __forceinline__ bf16x4 shfl8(bf16x4 v, int src) {
    union { bf16x4 b; int u[2]; } a;
    a.b = v;
    a.u[0] = __shfl(a.u[0], src, 64);
    a.u[1] = __shfl(a.u[1], src, 64);
    return a.b;
}

__device__ __forceinline__ bf16x8 combine8(bf16x4 lo, bf16x4 hi) {
    bf16x8 r;
    r[0] = lo[0]; r[1] = lo[1]; r[2] = lo[2]; r[3] = lo[3];
    r[4] = hi[0]; r[5] = hi[1]; r[6] = hi[2]; r[7] = hi[3];
    return r;
}

// ---------------------------------------------------------------------------
// Fused QKV + spatial attention. One block per (t,h): 1024 blocks x 256 thr
// (4 waves, 64 q-rows each). LDS = 64 KiB (2 blocks/CU):
//   k_s  [256 x 128B]  K (swizzled rows)  — written once, then read-only
//   vt_s [ 64 x 512B]  V^T (swizzled rows) — written once, then read-only
// NO LDS scratch: Q and P fragments are built by register shuffles.
//   - Q^T projection (swapped mfma) puts Q[q=l15][d in quad*4-chunks] in regs;
//     a 4-shfl cross-quad redistribution yields the B-fragment layout
//     Q[l15][kt*32+quad*8+e]. Same machinery redistributes P after softmax.
//   - PV is computed swapped too: O = mfma(V^T_frag, P_frag) gives lane
//     (l15,quad) reg r = O[q0+l15][dt*16+quad*4+r] -> direct f32x4 stores.
// Single __syncthreads() in the whole kernel; every LDS buffer is
// write-phase -> barrier -> read-only (the R2-proven-safe pattern).
// aw software pipeline: tile it+1's 16 float4 loads issue right after
// QK^T(it) consumes them; it=0's issue before the barrier.
// ---------------------------------------------------------------------------
__global__ __launch_bounds__(256, 2)
void fused_kernel(const float* __restrict__ x,
                  const float* __restrict__ Wq, const float* __restrict__ bq,
                  const float* __restrict__ Wk, const float* __restrict__ bk,
                  const float* __restrict__ Wv, const float* __restrict__ bv,
                  const float* __restrict__ aw, float* __restrict__ out) {
    __shared__ __align__(16) char k_s[256 * 128];   // 32 KiB
    __shared__ __align__(16) char vt_s[64 * 512];   // 32 KiB

    const int t    = blockIdx.x >> 3;
    const int h    = blockIdx.x & 7;
    const int wave = threadIdx.x >> 6;
    const int lane = threadIdx.x & 63;
    const int l15  = lane & 15, quad = lane >> 4;

    // cross-quad redistribution sources (see derivation in header comment)
    const int src1 = ((2 * quad) & 3) * 16 + l15;
    const int src2 = ((2 * quad + 1) & 3) * 16 + l15;
    const bool lowq = (quad < 2);

    // ---------------- phase 1: QKV projection ----------------
    // wave owns token rows 64w..64w+63 (4 m-tiles)
    bf16x8 ax[4][2];
#pragma unroll
    for (int mt = 0; mt < 4; ++mt) {
        int n = wave * 64 + mt * 16 + l15;
        const float* xp = x + ((size_t)n * TT + t) * DD;
#pragma unroll
        for (int kt = 0; kt < 2; ++kt)
            ax[mt][kt] = load_f32x8_as_bf16(xp + kt * 32 + quad * 8);
    }

    bf16x8 qf[4][2];  // Q B-fragments, one per q-tile (it)

    // --- Q: swapped projection -> Q^T frags in regs -> shuffle to B-layout ---
    {
        bf16x8 bw[4][2];
        f32x4 bqv[4];
#pragma unroll
        for (int dt = 0; dt < 4; ++dt) {
            const float* wp = Wq + ((size_t)(h * DD + dt * 16 + l15)) * DD;
#pragma unroll
            for (int kt = 0; kt < 2; ++kt)
                bw[dt][kt] = load_f32x8_as_bf16(wp + kt * 32 + quad * 8);
            bqv[dt] = *reinterpret_cast<const f32x4*>(bq + h * DD + dt * 16 + quad * 4);
        }
        // qpk[mt][dt][r] = bf16( (Q[tok mt*16+l15][d=dt*16+quad*4+r]+bias)/8 )
        bf16x4 qpk[4][4];
#pragma unroll
        for (int mt = 0; mt < 4; ++mt) {
#pragma unroll
            for (int dt = 0; dt < 4; ++dt) {
                f32x4 acc = {0.f, 0.f, 0.f, 0.f};
#pragma unroll
                for (int kt = 0; kt < 2; ++kt)
                    acc = __builtin_amdgcn_mfma_f32_16x16x32_bf16(
                        bw[dt][kt], ax[mt][kt], acc, 0, 0, 0);
#pragma unroll
                for (int r = 0; r < 4; ++r)
                    qpk[mt][dt][r] = (bf16_t)((acc[r] + bqv[dt][r]) * 0.125f);
            }
        }
        // redistribute: qf[it][kt][e] = Q[q0+l15][kt*32+quad*8+e]
#pragma unroll
        for (int it = 0; it < 4; ++it) {
#pragma unroll
            for (int kt = 0; kt < 2; ++kt) {
                bf16x4 ae = shfl8(qpk[it][2 * kt],     src1);
                bf16x4 be = shfl8(qpk[it][2 * kt],     src2);
                bf16x4 ce = shfl8(qpk[it][2 * kt + 1], src1);
                bf16x4 de = shfl8(qpk[it][2 * kt + 1], src2);
                qf[it][kt] = combine8(lowq ? ae : ce, lowq ? be : de);
            }
        }
    }

    // --- K: normal-orientation MFMA, C-frags straight into swizzled k_s ---
    {
        bf16x8 bw[4][2];
        float bias[4];
#pragma unroll
        for (int dt = 0; dt < 4; ++dt) {
            const float* wp = Wk + ((size_t)(h * DD + dt * 16 + l15)) * DD;
#pragma unroll
            for (int kt = 0; kt < 2; ++kt)
                bw[dt][kt] = load_f32x8_as_bf16(wp + kt * 32 + quad * 8);
            bias[dt] = bk[h * DD + dt * 16 + l15];
        }
#pragma unroll
        for (int mt = 0; mt < 4; ++mt) {
#pragma unroll
            for (int dt = 0; dt < 4; ++dt) {
                f32x4 acc = {0.f, 0.f, 0.f, 0.f};
#pragma unroll
                for (int kt = 0; kt < 2; ++kt)
                    acc = __builtin_amdgcn_mfma_f32_16x16x32_bf16(
                        ax[mt][kt], bw[dt][kt], acc, 0, 0, 0);
#pragma unroll
                for (int r = 0; r < 4; ++r) {
                    int n = wave * 64 + mt * 16 + quad * 4 + r;
                    *reinterpret_cast<bf16_t*>(k_s + swz(n, 128, (dt * 16 + l15) * 2)) =
                        (bf16_t)(acc[r] + bias[dt]);
                }
            }
        }
    }

    // --- V: swapped MFMA -> C[d][n], straight into swizzled vt_s ---
    {
        bf16x8 bw[4][2];
#pragma unroll
        for (int dt = 0; dt < 4; ++dt) {
            const float* wp = Wv + ((size_t)(h * DD + dt * 16 + l15)) * DD;
#pragma unroll
            for (int kt = 0; kt < 2; ++kt)
                bw[dt][kt] = load_f32x8_as_bf16(wp + kt * 32 + quad * 8);
        }
        f32x4 bvv[4];
#pragma unroll
        for (int dt = 0; dt < 4; ++dt)
            bvv[dt] = *reinterpret_cast<const f32x4*>(bv + h * DD + dt * 16 + quad * 4);
#pragma unroll
        for (int dt = 0; dt < 4; ++dt) {
#pragma unroll
            for (int mt = 0; mt < 4; ++mt) {
                f32x4 acc = {0.f, 0.f, 0.f, 0.f};
#pragma unroll
                for (int kt = 0; kt < 2; ++kt)
                    acc = __builtin_amdgcn_mfma_f32_16x16x32_bf16(
                        bw[dt][kt], ax[mt][kt], acc, 0, 0, 0);
#pragma unroll
                for (int r = 0; r < 4; ++r) {
                    int d  = dt * 16 + quad * 4 + r;
                    int cb = (wave * 64 + mt * 16 + l15) * 2;
                    *reinterpret_cast<bf16_t*>(vt_s + swz(d, 512, cb)) =
                        (bf16_t)(acc[r] + bvv[dt][r]);
                }
            }
        }
    }

    // prefetch aw for it=0 (global load, independent of LDS)
    const float* wp = aw + (size_t)blockIdx.x * ((size_t)NTOK * NTOK);
    f32x4 w4v[16];
    {
        const float* wrow = wp + (size_t)(wave * 64 + l15) * NTOK + quad * 4;
#pragma unroll
        for (int j = 0; j < 16; ++j)
            w4v[j] = *reinterpret_cast<const f32x4*>(wrow + j * 16);
    }

    __syncthreads();  // K/V visible to all waves; the ONLY barrier

    // ---------------- phase 2: attention, 4 q-tiles per wave ----------------
#pragma unroll
    for (int it = 0; it < 4; ++it) {
        const int q0 = wave * 64 + it * 16;

        // S^T: s[j][r] = S[q0+l15][j*16+quad*4+r] (swapped operands)
        f32x4 s[16];
        float mx = -1e30f;
        __builtin_amdgcn_s_setprio(1);
#pragma unroll
        for (int j = 0; j < 16; ++j) {
            f32x4 acc = {0.f, 0.f, 0.f, 0.f};
#pragma unroll
            for (int kt = 0; kt < 2; ++kt) {
                int kn = j * 16 + l15;
                bf16x8 kf = *reinterpret_cast<const bf16x8*>(
                    k_s + swz(kn, 128, kt * 64 + quad * 16));
                acc = __builtin_amdgcn_mfma_f32_16x16x32_bf16(kf, qf[it][kt], acc, 0, 0, 0);
            }
            acc *= w4v[j];
            s[j] = acc;
            mx = fmaxf(mx, fmaxf(fmaxf(acc[0], acc[1]), fmaxf(acc[2], acc[3])));
        }
        __builtin_amdgcn_s_setprio(0);

        // w4v consumed -> issue next q-tile's aw loads; latency hides under
        // softmax + shuffles + PV.
        if (it < 3) {
            const float* wrow = wp + (size_t)(q0 + 16 + l15) * NTOK + quad * 4;
#pragma unroll
            for (int j = 0; j < 16; ++j)
                w4v[j] = *reinterpret_cast<const f32x4*>(wrow + j * 16);
        }

        mx = fmaxf(mx, __shfl_xor(mx, 16, 64));
        mx = fmaxf(mx, __shfl_xor(mx, 32, 64));

        float sm = 0.f;
#pragma unroll
        for (int j = 0; j < 16; ++j) {
#pragma unroll
            for (int r = 0; r < 4; ++r) {
                float e = __expf(s[j][r] - mx);
                s[j][r] = e;
                sm += e;
            }
        }
        sm += __shfl_xor(sm, 16, 64);
        sm += __shfl_xor(sm, 32, 64);
        const float inv = 1.f / sm;

        // pack P rows to bf16x4 (lane owns q-row l15, cols j*16+quad*4+r)
        bf16x4 ppk[16];
#pragma unroll
        for (int j = 0; j < 16; ++j) {
#pragma unroll
            for (int r = 0; r < 4; ++r)
                ppk[j][r] = (bf16_t)(s[j][r] * inv);
        }

        // O = P V, swapped: o[dt] reg r = O[q0+l15][dt*16+quad*4+r]
        f32x4 o[4];
#pragma unroll
        for (int dt = 0; dt < 4; ++dt) o[dt] = (f32x4){0.f, 0.f, 0.f, 0.f};
#pragma unroll
        for (int kt = 0; kt < 8; ++kt) {
            // P B-frag via cross-quad redistribution (register shuffles)
            bf16x4 ae = shfl8(ppk[2 * kt],     src1);
            bf16x4 be = shfl8(ppk[2 * kt],     src2);
            bf16x4 ce = shfl8(ppk[2 * kt + 1], src1);
            bf16x4 de = shfl8(ppk[2 * kt + 1], src2);
            bf16x8 pf = combine8(lowq ? ae : ce, lowq ? be : de);
            __builtin_amdgcn_s_setprio(1);
#pragma unroll
            for (int dt = 0; dt < 4; ++dt) {
                bf16x8 vf = *reinterpret_cast<const bf16x8*>(
                    vt_s + swz(dt * 16 + l15, 512, kt * 64 + quad * 16));
                o[dt] = __builtin_amdgcn_mfma_f32_16x16x32_bf16(vf, pf, o[dt], 0, 0, 0);
            }
            __builtin_amdgcn_s_setprio(0);
        }

        // direct coalesced stores: lane (l15,quad) owns q-row q0+l15,
        // d-chunk dt*16+quad*4..+3
        float* orow = out + (((size_t)h * NTOK + q0 + l15) * TT + t) * DD;
#pragma unroll
        for (int dt = 0; dt < 4; ++dt)
            *reinterpret_cast<f32x4*>(orow + dt * 16 + quad * 4) = o[dt];
    }
}

extern "C" void kernel_launch(void* const* d_in, const int* in_sizes, int n_in,
                              void* d_out, int out_size, void* d_ws, size_t ws_size,
                              hipStream_t stream) {
    const float* x  = (const float*)d_in[0];
    const float* Wq = (const float*)d_in[1];
    const float* bq = (const float*)d_in[2];
    const float* Wk = (const float*)d_in[3];
    const float* bk = (const float*)d_in[4];
    const float* Wv = (const float*)d_in[5];
    const float* bv = (const float*)d_in[6];
    const float* aw = (const float*)d_in[7];
    float* out = (float*)d_out;

    fused_kernel<<<TT * HH, 256, 0, stream>>>(x, Wq, bq, Wk, bk, Wv, bv, aw, out);
}